// Round 1
// baseline (669.794 us; speedup 1.0000x reference)
//
#include <hip/hip_runtime.h>
#include <cstddef>
#include <cstdint>

#define BATCH 32

// Workspace layout (floats):
//   T  : 5 * 4,194,304 = 20,971,520   (Cheb polynomials T1..T5, max at layer 1)
//   Y  : 16,777,216                    (conv output, max at layer 0)
//   Xa : 4,194,304                     (pooled ping)
//   Xb : 1,048,576                     (pooled pong)
//   H  : 4,096                         (encoder hidden)
// total ~43.0M floats = ~172 MB

// ---------------- Chebyshev recurrence step, FIN=3 (layer 0) ----------------
// Tout[b,n,:] = coef * sum_{d<6} Tin[b, ec[6n+d], :] + beta * Tpp[b,n,:]
template<int N>
__global__ void __launch_bounds__(256) cheb_step_f3(
    const float* __restrict__ Tin, const float* __restrict__ Tpp,
    const int* __restrict__ ec, float* __restrict__ Tout,
    float coef, float beta)
{
  int g = blockIdx.x * 256 + threadIdx.x;   // b*N + n
  if (g >= BATCH * N) return;
  int b = g / N;
  int n = g % N;
  const int* e = ec + n * 6;
  const float* Tb = Tin + (size_t)b * N * 3;
  float s0 = 0.f, s1 = 0.f, s2 = 0.f;
#pragma unroll
  for (int d = 0; d < 6; ++d) {
    int c = e[d];
    const float* p = Tb + (size_t)c * 3;
    s0 += p[0]; s1 += p[1]; s2 += p[2];
  }
  size_t o = (size_t)g * 3;
  Tout[o + 0] = coef * s0 + beta * Tpp[o + 0];
  Tout[o + 1] = coef * s1 + beta * Tpp[o + 1];
  Tout[o + 2] = coef * s2 + beta * Tpp[o + 2];
}

// ---------------- Chebyshev recurrence step, FIN divisible by 4 ----------------
template<int N, int FIN>
__global__ void __launch_bounds__(256) cheb_step_v(
    const float* __restrict__ Tin, const float* __restrict__ Tpp,
    const int* __restrict__ ec, float* __restrict__ Tout,
    float coef, float beta)
{
  constexpr int F4 = FIN / 4;
  int idx = blockIdx.x * 256 + threadIdx.x;      // float4 index into [B][N][FIN]
  if (idx >= BATCH * N * F4) return;
  int g  = idx / F4;     // b*N + n
  int f4 = idx % F4;
  int n = g % N;
  int b = g / N;
  const int* e = ec + n * 6;
  const float4* Tin4 = (const float4*)Tin;
  float4 s = make_float4(0.f, 0.f, 0.f, 0.f);
#pragma unroll
  for (int d = 0; d < 6; ++d) {
    int c = e[d];
    float4 v = Tin4[(size_t)(b * N + c) * F4 + f4];
    s.x += v.x; s.y += v.y; s.z += v.z; s.w += v.w;
  }
  float4 p = ((const float4*)Tpp)[idx];
  float4 r;
  r.x = coef * s.x + beta * p.x;
  r.y = coef * s.y + beta * p.y;
  r.z = coef * s.z + beta * p.z;
  r.w = coef * s.w + beta * p.w;
  ((float4*)Tout)[idx] = r;
}

// ---------------- fused Cheb matmul + bias + relu ----------------
// out[b,n,fo] = relu( bias[fo] + sum_k sum_f T_k[b,n,f] * W[k,f,fo] ), T_0 = X
template<int N, int FIN, int FOUT>
__global__ void __launch_bounds__(256) cheb_matmul_relu(
    const float* __restrict__ X, const float* __restrict__ T,
    const float* __restrict__ W, const float* __restrict__ bias,
    float* __restrict__ out)
{
  constexpr int BN = BATCH * N;
  int g = blockIdx.x * 256 + threadIdx.x;     // node index b*N+n
  if (g >= BN) return;
  float acc[FOUT];
#pragma unroll
  for (int fo = 0; fo < FOUT; ++fo) acc[fo] = bias[fo];
  {
    const float* t0 = X + (size_t)g * FIN;
#pragma unroll
    for (int f = 0; f < FIN; ++f) {
      float t = t0[f];
#pragma unroll
      for (int fo = 0; fo < FOUT; ++fo) acc[fo] += t * W[f * FOUT + fo];
    }
  }
#pragma unroll 1
  for (int k = 1; k < 6; ++k) {
    const float* tk = T + ((size_t)(k - 1) * BN + g) * FIN;
    const float* wk = W + k * FIN * FOUT;
#pragma unroll
    for (int f = 0; f < FIN; ++f) {
      float t = tk[f];
#pragma unroll
      for (int fo = 0; fo < FOUT; ++fo) acc[fo] += t * wk[f * FOUT + fo];
    }
  }
  float* o = out + (size_t)g * FOUT;
#pragma unroll
  for (int fo = 0; fo < FOUT; ++fo) o[fo] = fmaxf(acc[fo], 0.0f);
}

// ---------------- pool: Xout[b,m,:] = sum_{j<3} pv[3m+j] * Y[b, pc[3m+j], :] ----------------
template<int N, int M, int F>
__global__ void __launch_bounds__(256) pool_kernel(
    const float* __restrict__ Y, const int* __restrict__ pc,
    const float* __restrict__ pv, float* __restrict__ Xout)
{
  constexpr int F4 = F / 4;
  int idx = blockIdx.x * 256 + threadIdx.x;   // float4 index into [B][M][F]
  if (idx >= BATCH * M * F4) return;
  int g  = idx / F4;    // b*M + m
  int f4 = idx % F4;
  int m = g % M;
  int b = g / M;
  const float4* Y4 = (const float4*)Y;
  float4 acc = make_float4(0.f, 0.f, 0.f, 0.f);
#pragma unroll
  for (int j = 0; j < 3; ++j) {
    int c = pc[m * 3 + j];
    float v = pv[m * 3 + j];
    float4 t = Y4[(size_t)(b * N + c) * F4 + f4];
    acc.x += v * t.x; acc.y += v * t.y; acc.z += v * t.z; acc.w += v * t.w;
  }
  ((float4*)Xout)[idx] = acc;
}

// ---------------- encoder: H[b,:] = relu(Xf[b,:] @ encW + encB), Xf: [32,4096] ----------------
__global__ void __launch_bounds__(256) encoder_kernel(
    const float* __restrict__ Xf, const float* __restrict__ encW,
    const float* __restrict__ encB, float* __restrict__ H)
{
  int b = blockIdx.x;
  int fo = threadIdx.x & 127;
  int half = threadIdx.x >> 7;     // 0 or 1
  const float* xr = Xf + b * 4096 + half * 2048;
  const float* w  = encW + (size_t)half * 2048 * 128;
  float acc = 0.f;
#pragma unroll 4
  for (int i = 0; i < 2048; ++i) acc += xr[i] * w[(size_t)i * 128 + fo];
  __shared__ float part[256];
  part[threadIdx.x] = acc;
  __syncthreads();
  if (half == 0) {
    H[b * 128 + fo] = fmaxf(part[fo] + part[128 + fo] + encB[fo], 0.f);
  }
}

// ---------------- classifier: out[b,c] = H[b,:] @ clsW[:,c] + clsB[c] ----------------
__global__ void __launch_bounds__(256) classifier_kernel(
    const float* __restrict__ H, const float* __restrict__ clsW,
    const float* __restrict__ clsB, float* __restrict__ out)
{
  int t = blockIdx.x * 256 + threadIdx.x;
  if (t >= 320) return;
  int b = t / 10;
  int c = t % 10;
  float acc = clsB[c];
#pragma unroll 4
  for (int f = 0; f < 128; ++f) acc += H[b * 128 + f] * clsW[f * 10 + c];
  out[t] = acc;
}

extern "C" void kernel_launch(void* const* d_in, const int* in_sizes, int n_in,
                              void* d_out, int out_size, void* d_ws, size_t ws_size,
                              hipStream_t stream)
{
  const float* x   = (const float*)d_in[0];
  const int* ec0 = (const int*)d_in[2];
  const int* ec1 = (const int*)d_in[4];
  const int* ec2 = (const int*)d_in[6];
  const int* ec3 = (const int*)d_in[8];
  const int* pc0 = (const int*)d_in[10]; const float* pv0 = (const float*)d_in[11];
  const int* pc1 = (const int*)d_in[13]; const float* pv1 = (const float*)d_in[14];
  const int* pc2 = (const int*)d_in[16]; const float* pv2 = (const float*)d_in[17];
  const int* pc3 = (const int*)d_in[19]; const float* pv3 = (const float*)d_in[20];
  const float* W0 = (const float*)d_in[21]; const float* b0 = (const float*)d_in[22];
  const float* W1 = (const float*)d_in[23]; const float* b1 = (const float*)d_in[24];
  const float* W2 = (const float*)d_in[25]; const float* b2 = (const float*)d_in[26];
  const float* W3 = (const float*)d_in[27]; const float* b3 = (const float*)d_in[28];
  const float* encW = (const float*)d_in[29]; const float* encB = (const float*)d_in[30];
  const float* clsW = (const float*)d_in[31]; const float* clsB = (const float*)d_in[32];
  float* out = (float*)d_out;

  float* ws = (float*)d_ws;
  float* T  = ws;                    // 20,971,520 floats
  float* Y  = ws + 20971520;         // 16,777,216
  float* Xa = Y + 16777216;          // 4,194,304
  float* Xb = Xa + 4194304;          // 1,048,576
  float* H  = Xb + 1048576;          // 4,096

  const float cI = -1.0f / 6.0f;     // T1 = L x  = -1/6 * gather-sum
  const float cS = -1.0f / 3.0f;     // Tk = 2 L T(k-1) - T(k-2)

  // ================= layer 0: N=16384, FIN=3, FOUT=32, M=4096 =================
  {
    constexpr int N = 16384;
    constexpr int BN = BATCH * N;          // 524288
    const size_t S = (size_t)BN * 3;       // T slice stride
    dim3 gs(BN / 256), blk(256);
    cheb_step_f3<N><<<gs, blk, 0, stream>>>(x,         x,         ec0, T,         cI,  0.f);
    cheb_step_f3<N><<<gs, blk, 0, stream>>>(T,         x,         ec0, T + S,     cS, -1.f);
    cheb_step_f3<N><<<gs, blk, 0, stream>>>(T + S,     T,         ec0, T + 2 * S, cS, -1.f);
    cheb_step_f3<N><<<gs, blk, 0, stream>>>(T + 2 * S, T + S,     ec0, T + 3 * S, cS, -1.f);
    cheb_step_f3<N><<<gs, blk, 0, stream>>>(T + 3 * S, T + 2 * S, ec0, T + 4 * S, cS, -1.f);
    cheb_matmul_relu<N, 3, 32><<<dim3(BN / 256), blk, 0, stream>>>(x, T, W0, b0, Y);
    pool_kernel<N, 4096, 32><<<dim3((BATCH * 4096 * 8) / 256), blk, 0, stream>>>(Y, pc0, pv0, Xa);
  }
  // ================= layer 1: N=4096, FIN=32, FOUT=32, M=1024 =================
  {
    constexpr int N = 4096;
    constexpr int BN = BATCH * N;          // 131072
    const size_t S = (size_t)BN * 32;
    dim3 gs((BN * 8) / 256), blk(256);
    cheb_step_v<N, 32><<<gs, blk, 0, stream>>>(Xa,        Xa,        ec1, T,         cI,  0.f);
    cheb_step_v<N, 32><<<gs, blk, 0, stream>>>(T,         Xa,        ec1, T + S,     cS, -1.f);
    cheb_step_v<N, 32><<<gs, blk, 0, stream>>>(T + S,     T,         ec1, T + 2 * S, cS, -1.f);
    cheb_step_v<N, 32><<<gs, blk, 0, stream>>>(T + 2 * S, T + S,     ec1, T + 3 * S, cS, -1.f);
    cheb_step_v<N, 32><<<gs, blk, 0, stream>>>(T + 3 * S, T + 2 * S, ec1, T + 4 * S, cS, -1.f);
    cheb_matmul_relu<N, 32, 32><<<dim3(BN / 256), blk, 0, stream>>>(Xa, T, W1, b1, Y);
    pool_kernel<N, 1024, 32><<<dim3((BATCH * 1024 * 8) / 256), blk, 0, stream>>>(Y, pc1, pv1, Xb);
  }
  // ================= layer 2: N=1024, FIN=32, FOUT=32, M=256 =================
  {
    constexpr int N = 1024;
    constexpr int BN = BATCH * N;          // 32768
    const size_t S = (size_t)BN * 32;
    dim3 gs((BN * 8) / 256), blk(256);
    cheb_step_v<N, 32><<<gs, blk, 0, stream>>>(Xb,        Xb,        ec2, T,         cI,  0.f);
    cheb_step_v<N, 32><<<gs, blk, 0, stream>>>(T,         Xb,        ec2, T + S,     cS, -1.f);
    cheb_step_v<N, 32><<<gs, blk, 0, stream>>>(T + S,     T,         ec2, T + 2 * S, cS, -1.f);
    cheb_step_v<N, 32><<<gs, blk, 0, stream>>>(T + 2 * S, T + S,     ec2, T + 3 * S, cS, -1.f);
    cheb_step_v<N, 32><<<gs, blk, 0, stream>>>(T + 3 * S, T + 2 * S, ec2, T + 4 * S, cS, -1.f);
    cheb_matmul_relu<N, 32, 32><<<dim3(BN / 256), blk, 0, stream>>>(Xb, T, W2, b2, Y);
    pool_kernel<N, 256, 32><<<dim3((BATCH * 256 * 8) / 256), blk, 0, stream>>>(Y, pc2, pv2, Xa);
  }
  // ================= layer 3: N=256, FIN=32, FOUT=64, M=64 =================
  {
    constexpr int N = 256;
    constexpr int BN = BATCH * N;          // 8192
    const size_t S = (size_t)BN * 32;
    dim3 gs((BN * 8) / 256), blk(256);
    cheb_step_v<N, 32><<<gs, blk, 0, stream>>>(Xa,        Xa,        ec3, T,         cI,  0.f);
    cheb_step_v<N, 32><<<gs, blk, 0, stream>>>(T,         Xa,        ec3, T + S,     cS, -1.f);
    cheb_step_v<N, 32><<<gs, blk, 0, stream>>>(T + S,     T,         ec3, T + 2 * S, cS, -1.f);
    cheb_step_v<N, 32><<<gs, blk, 0, stream>>>(T + 2 * S, T + S,     ec3, T + 3 * S, cS, -1.f);
    cheb_step_v<N, 32><<<gs, blk, 0, stream>>>(T + 3 * S, T + 2 * S, ec3, T + 4 * S, cS, -1.f);
    cheb_matmul_relu<N, 32, 64><<<dim3(BN / 256), blk, 0, stream>>>(Xa, T, W3, b3, Y);
    pool_kernel<N, 64, 64><<<dim3((BATCH * 64 * 16) / 256), blk, 0, stream>>>(Y, pc3, pv3, Xb);
  }
  // ================= head =================
  encoder_kernel<<<dim3(32), dim3(256), 0, stream>>>(Xb, encW, encB, H);
  classifier_kernel<<<dim3(2), dim3(256), 0, stream>>>(H, clsW, clsB, out);
}

// Round 2
// 550.153 us; speedup vs baseline: 1.2175x; 1.2175x over previous
//
#include <hip/hip_runtime.h>
#include <cstddef>
#include <cstdint>

#define BATCH 32

// Workspace layout (floats):
//   T  : 5 * 4,194,304 = 20,971,520   (Cheb polynomials T1..T5, max at layer 1)
//   Y  : 16,777,216                    (conv output, max at layer 0)
//   Xa : 4,194,304                     (pooled ping)
//   Xb : 1,048,576                     (pooled pong)
//   H  : 4,096                         (encoder hidden)
//   P  : 65,536                        (encoder split-K partials)

// ---------------- Chebyshev recurrence step, FIN=3 (layer 0) ----------------
// Tout[b,n,:] = coef * sum_{d<6} Tin[b, ec[6n+d], :] + beta * Tpp[b,n,:]
template<int N>
__global__ void __launch_bounds__(256) cheb_step_f3(
    const float* __restrict__ Tin, const float* __restrict__ Tpp,
    const int* __restrict__ ec, float* __restrict__ Tout,
    float coef, float beta)
{
  int g = blockIdx.x * 256 + threadIdx.x;   // b*N + n
  if (g >= BATCH * N) return;
  int b = g / N;
  int n = g % N;
  const int* e = ec + n * 6;
  const float* Tb = Tin + (size_t)b * N * 3;
  float s0 = 0.f, s1 = 0.f, s2 = 0.f;
#pragma unroll
  for (int d = 0; d < 6; ++d) {
    int c = e[d];
    const float* p = Tb + (size_t)c * 3;
    s0 += p[0]; s1 += p[1]; s2 += p[2];
  }
  size_t o = (size_t)g * 3;
  Tout[o + 0] = coef * s0 + beta * Tpp[o + 0];
  Tout[o + 1] = coef * s1 + beta * Tpp[o + 1];
  Tout[o + 2] = coef * s2 + beta * Tpp[o + 2];
}

// ---------------- Chebyshev recurrence step, FIN divisible by 4 ----------------
template<int N, int FIN>
__global__ void __launch_bounds__(256) cheb_step_v(
    const float* __restrict__ Tin, const float* __restrict__ Tpp,
    const int* __restrict__ ec, float* __restrict__ Tout,
    float coef, float beta)
{
  constexpr int F4 = FIN / 4;
  int idx = blockIdx.x * 256 + threadIdx.x;      // float4 index into [B][N][FIN]
  if (idx >= BATCH * N * F4) return;
  int g  = idx / F4;     // b*N + n
  int f4 = idx % F4;
  int n = g % N;
  int b = g / N;
  const int* e = ec + n * 6;
  const float4* Tin4 = (const float4*)Tin;
  float4 s = make_float4(0.f, 0.f, 0.f, 0.f);
#pragma unroll
  for (int d = 0; d < 6; ++d) {
    int c = e[d];
    float4 v = Tin4[(size_t)(b * N + c) * F4 + f4];
    s.x += v.x; s.y += v.y; s.z += v.z; s.w += v.w;
  }
  float4 p = ((const float4*)Tpp)[idx];
  float4 r;
  r.x = coef * s.x + beta * p.x;
  r.y = coef * s.y + beta * p.y;
  r.z = coef * s.z + beta * p.z;
  r.w = coef * s.w + beta * p.w;
  ((float4*)Tout)[idx] = r;
}

// ---------------- fused Cheb matmul + bias + relu ----------------
// out[b,n,fo] = relu( bias[fo] + sum_k sum_f T_k[b,n,f] * W[k,f,fo] ), T_0 = X
template<int N, int FIN, int FOUT>
__global__ void __launch_bounds__(256) cheb_matmul_relu(
    const float* __restrict__ X, const float* __restrict__ T,
    const float* __restrict__ W, const float* __restrict__ bias,
    float* __restrict__ out)
{
  constexpr int BN = BATCH * N;
  int g = blockIdx.x * 256 + threadIdx.x;     // node index b*N+n
  if (g >= BN) return;
  float acc[FOUT];
#pragma unroll
  for (int fo = 0; fo < FOUT; ++fo) acc[fo] = bias[fo];
  {
    const float* t0 = X + (size_t)g * FIN;
#pragma unroll
    for (int f = 0; f < FIN; ++f) {
      float t = t0[f];
#pragma unroll
      for (int fo = 0; fo < FOUT; ++fo) acc[fo] += t * W[f * FOUT + fo];
    }
  }
#pragma unroll 1
  for (int k = 1; k < 6; ++k) {
    const float* tk = T + ((size_t)(k - 1) * BN + g) * FIN;
    const float* wk = W + k * FIN * FOUT;
#pragma unroll
    for (int f = 0; f < FIN; ++f) {
      float t = tk[f];
#pragma unroll
      for (int fo = 0; fo < FOUT; ++fo) acc[fo] += t * wk[f * FOUT + fo];
    }
  }
  float* o = out + (size_t)g * FOUT;
#pragma unroll
  for (int fo = 0; fo < FOUT; ++fo) o[fo] = fmaxf(acc[fo], 0.0f);
}

// ---------------- pool: Xout[b,m,:] = sum_{j<3} pv[3m+j] * Y[b, pc[3m+j], :] ----------------
template<int N, int M, int F>
__global__ void __launch_bounds__(256) pool_kernel(
    const float* __restrict__ Y, const int* __restrict__ pc,
    const float* __restrict__ pv, float* __restrict__ Xout)
{
  constexpr int F4 = F / 4;
  int idx = blockIdx.x * 256 + threadIdx.x;   // float4 index into [B][M][F]
  if (idx >= BATCH * M * F4) return;
  int g  = idx / F4;    // b*M + m
  int f4 = idx % F4;
  int m = g % M;
  int b = g / M;
  const float4* Y4 = (const float4*)Y;
  float4 acc = make_float4(0.f, 0.f, 0.f, 0.f);
#pragma unroll
  for (int j = 0; j < 3; ++j) {
    int c = pc[m * 3 + j];
    float v = pv[m * 3 + j];
    float4 t = Y4[(size_t)(b * N + c) * F4 + f4];
    acc.x += v * t.x; acc.y += v * t.y; acc.z += v * t.z; acc.w += v * t.w;
  }
  ((float4*)Xout)[idx] = acc;
}

// ---------------- encoder split-K partial ----------------
// partial[b][ks][fo] = sum_{i in rows(ks)} Xf[b,i] * encW[i,fo]
// grid: (32 b, 16 ks), 512 blocks -> full-chip occupancy (was 32 blocks, 1.5%)
__global__ void __launch_bounds__(256) encoder_partial(
    const float* __restrict__ Xf, const float* __restrict__ encW,
    float* __restrict__ partial)
{
  int b  = blockIdx.x;        // 0..31
  int ks = blockIdx.y;        // 0..15
  int fo = threadIdx.x & 127;
  int half = threadIdx.x >> 7;   // 0/1 splits the 256 rows of this chunk
  const float* xr = Xf + b * 4096 + ks * 256 + half * 128;
  const float* w  = encW + (size_t)(ks * 256 + half * 128) * 128;
  float acc = 0.f;
#pragma unroll 8
  for (int i = 0; i < 128; ++i) acc += xr[i] * w[(size_t)i * 128 + fo];
  __shared__ float part[256];
  part[threadIdx.x] = acc;
  __syncthreads();
  if (half == 0) partial[(size_t)(b * 16 + ks) * 128 + fo] = part[fo] + part[128 + fo];
}

// ---------------- encoder reduce: H[b,fo] = relu(sum_ks partial + bias) ----------------
__global__ void __launch_bounds__(256) encoder_reduce(
    const float* __restrict__ partial, const float* __restrict__ encB,
    float* __restrict__ H)
{
  int t = blockIdx.x * 256 + threadIdx.x;   // b*128 + fo, 4096 total
  if (t >= 32 * 128) return;
  int b = t >> 7, fo = t & 127;
  float acc = encB[fo];
#pragma unroll
  for (int ks = 0; ks < 16; ++ks) acc += partial[(size_t)(b * 16 + ks) * 128 + fo];
  H[t] = fmaxf(acc, 0.f);
}

// ---------------- classifier: out[b,c] = H[b,:] @ clsW[:,c] + clsB[c] ----------------
__global__ void __launch_bounds__(256) classifier_kernel(
    const float* __restrict__ H, const float* __restrict__ clsW,
    const float* __restrict__ clsB, float* __restrict__ out)
{
  int t = blockIdx.x * 256 + threadIdx.x;
  if (t >= 320) return;
  int b = t / 10;
  int c = t % 10;
  float acc = clsB[c];
#pragma unroll 4
  for (int f = 0; f < 128; ++f) acc += H[b * 128 + f] * clsW[f * 10 + c];
  out[t] = acc;
}

extern "C" void kernel_launch(void* const* d_in, const int* in_sizes, int n_in,
                              void* d_out, int out_size, void* d_ws, size_t ws_size,
                              hipStream_t stream)
{
  const float* x   = (const float*)d_in[0];
  const int* ec0 = (const int*)d_in[2];
  const int* ec1 = (const int*)d_in[4];
  const int* ec2 = (const int*)d_in[6];
  const int* ec3 = (const int*)d_in[8];
  const int* pc0 = (const int*)d_in[10]; const float* pv0 = (const float*)d_in[11];
  const int* pc1 = (const int*)d_in[13]; const float* pv1 = (const float*)d_in[14];
  const int* pc2 = (const int*)d_in[16]; const float* pv2 = (const float*)d_in[17];
  const int* pc3 = (const int*)d_in[19]; const float* pv3 = (const float*)d_in[20];
  const float* W0 = (const float*)d_in[21]; const float* b0 = (const float*)d_in[22];
  const float* W1 = (const float*)d_in[23]; const float* b1 = (const float*)d_in[24];
  const float* W2 = (const float*)d_in[25]; const float* b2 = (const float*)d_in[26];
  const float* W3 = (const float*)d_in[27]; const float* b3 = (const float*)d_in[28];
  const float* encW = (const float*)d_in[29]; const float* encB = (const float*)d_in[30];
  const float* clsW = (const float*)d_in[31]; const float* clsB = (const float*)d_in[32];
  float* out = (float*)d_out;

  float* ws = (float*)d_ws;
  float* T  = ws;                    // 20,971,520 floats
  float* Y  = ws + 20971520;         // 16,777,216
  float* Xa = Y + 16777216;          // 4,194,304
  float* Xb = Xa + 4194304;          // 1,048,576
  float* H  = Xb + 1048576;          // 4,096
  float* P  = H + 4096;              // 65,536 encoder partials

  const float cI = -1.0f / 6.0f;     // T1 = L x  = -1/6 * gather-sum
  const float cS = -1.0f / 3.0f;     // Tk = 2 L T(k-1) - T(k-2)

  // ================= layer 0: N=16384, FIN=3, FOUT=32, M=4096 =================
  {
    constexpr int N = 16384;
    constexpr int BN = BATCH * N;          // 524288
    const size_t S = (size_t)BN * 3;       // T slice stride
    dim3 gs(BN / 256), blk(256);
    cheb_step_f3<N><<<gs, blk, 0, stream>>>(x,         x,         ec0, T,         cI,  0.f);
    cheb_step_f3<N><<<gs, blk, 0, stream>>>(T,         x,         ec0, T + S,     cS, -1.f);
    cheb_step_f3<N><<<gs, blk, 0, stream>>>(T + S,     T,         ec0, T + 2 * S, cS, -1.f);
    cheb_step_f3<N><<<gs, blk, 0, stream>>>(T + 2 * S, T + S,     ec0, T + 3 * S, cS, -1.f);
    cheb_step_f3<N><<<gs, blk, 0, stream>>>(T + 3 * S, T + 2 * S, ec0, T + 4 * S, cS, -1.f);
    cheb_matmul_relu<N, 3, 32><<<dim3(BN / 256), blk, 0, stream>>>(x, T, W0, b0, Y);
    pool_kernel<N, 4096, 32><<<dim3((BATCH * 4096 * 8) / 256), blk, 0, stream>>>(Y, pc0, pv0, Xa);
  }
  // ================= layer 1: N=4096, FIN=32, FOUT=32, M=1024 =================
  {
    constexpr int N = 4096;
    constexpr int BN = BATCH * N;          // 131072
    const size_t S = (size_t)BN * 32;
    dim3 gs((BN * 8) / 256), blk(256);
    cheb_step_v<N, 32><<<gs, blk, 0, stream>>>(Xa,        Xa,        ec1, T,         cI,  0.f);
    cheb_step_v<N, 32><<<gs, blk, 0, stream>>>(T,         Xa,        ec1, T + S,     cS, -1.f);
    cheb_step_v<N, 32><<<gs, blk, 0, stream>>>(T + S,     T,         ec1, T + 2 * S, cS, -1.f);
    cheb_step_v<N, 32><<<gs, blk, 0, stream>>>(T + 2 * S, T + S,     ec1, T + 3 * S, cS, -1.f);
    cheb_step_v<N, 32><<<gs, blk, 0, stream>>>(T + 3 * S, T + 2 * S, ec1, T + 4 * S, cS, -1.f);
    cheb_matmul_relu<N, 32, 32><<<dim3(BN / 256), blk, 0, stream>>>(Xa, T, W1, b1, Y);
    pool_kernel<N, 1024, 32><<<dim3((BATCH * 1024 * 8) / 256), blk, 0, stream>>>(Y, pc1, pv1, Xb);
  }
  // ================= layer 2: N=1024, FIN=32, FOUT=32, M=256 =================
  {
    constexpr int N = 1024;
    constexpr int BN = BATCH * N;          // 32768
    const size_t S = (size_t)BN * 32;
    dim3 gs((BN * 8) / 256), blk(256);
    cheb_step_v<N, 32><<<gs, blk, 0, stream>>>(Xb,        Xb,        ec2, T,         cI,  0.f);
    cheb_step_v<N, 32><<<gs, blk, 0, stream>>>(T,         Xb,        ec2, T + S,     cS, -1.f);
    cheb_step_v<N, 32><<<gs, blk, 0, stream>>>(T + S,     T,         ec2, T + 2 * S, cS, -1.f);
    cheb_step_v<N, 32><<<gs, blk, 0, stream>>>(T + 2 * S, T + S,     ec2, T + 3 * S, cS, -1.f);
    cheb_step_v<N, 32><<<gs, blk, 0, stream>>>(T + 3 * S, T + 2 * S, ec2, T + 4 * S, cS, -1.f);
    cheb_matmul_relu<N, 32, 32><<<dim3(BN / 256), blk, 0, stream>>>(Xb, T, W2, b2, Y);
    pool_kernel<N, 256, 32><<<dim3((BATCH * 256 * 8) / 256), blk, 0, stream>>>(Y, pc2, pv2, Xa);
  }
  // ================= layer 3: N=256, FIN=32, FOUT=64, M=64 =================
  {
    constexpr int N = 256;
    constexpr int BN = BATCH * N;          // 8192
    const size_t S = (size_t)BN * 32;
    dim3 gs((BN * 8) / 256), blk(256);
    cheb_step_v<N, 32><<<gs, blk, 0, stream>>>(Xa,        Xa,        ec3, T,         cI,  0.f);
    cheb_step_v<N, 32><<<gs, blk, 0, stream>>>(T,         Xa,        ec3, T + S,     cS, -1.f);
    cheb_step_v<N, 32><<<gs, blk, 0, stream>>>(T + S,     T,         ec3, T + 2 * S, cS, -1.f);
    cheb_step_v<N, 32><<<gs, blk, 0, stream>>>(T + 2 * S, T + S,     ec3, T + 3 * S, cS, -1.f);
    cheb_step_v<N, 32><<<gs, blk, 0, stream>>>(T + 3 * S, T + 2 * S, ec3, T + 4 * S, cS, -1.f);
    cheb_matmul_relu<N, 32, 64><<<dim3(BN / 256), blk, 0, stream>>>(Xa, T, W3, b3, Y);
    pool_kernel<N, 64, 64><<<dim3((BATCH * 64 * 16) / 256), blk, 0, stream>>>(Y, pc3, pv3, Xb);
  }
  // ================= head =================
  encoder_partial<<<dim3(32, 16), dim3(256), 0, stream>>>(Xb, encW, P);
  encoder_reduce<<<dim3(16), dim3(256), 0, stream>>>(P, encB, H);
  classifier_kernel<<<dim3(2), dim3(256), 0, stream>>>(H, clsW, clsB, out);
}

// Round 3
// 408.381 us; speedup vs baseline: 1.6401x; 1.3472x over previous
//
#include <hip/hip_runtime.h>
#include <cstddef>
#include <cstdint>

#define BATCH 32

// Workspace layout (floats):
//   T  : 20,971,520  (Cheb polynomials T1..T5; max at layer 1: 5 * 4,194,304)
//   Xa : 4,194,304   (pooled ping: layer0 out [32,4096,32], layer2 out reuses)
//   Xb : 1,048,576   (pooled pong: layer1 out [32,1024,32], layer3 out reuses)
//   P  : 65,536      (encoder split-K partials)

__device__ __forceinline__ void fma4(float4& a, float s, const float4& w) {
  a.x += s * w.x; a.y += s * w.y; a.z += s * w.z; a.w += s * w.w;
}
__device__ __forceinline__ float4 relu4(const float4& a) {
  return make_float4(fmaxf(a.x, 0.f), fmaxf(a.y, 0.f), fmaxf(a.z, 0.f), fmaxf(a.w, 0.f));
}

// ---------------- Chebyshev recurrence step, FIN=3 (layer 0) ----------------
// Tout[b,n,:] = coef * sum_{d<6} Tin[b, ec[6n+d], :] + beta * Tpp[b,n,:]
template<int N>
__global__ void __launch_bounds__(256) cheb_step_f3(
    const float* __restrict__ Tin, const float* __restrict__ Tpp,
    const int* __restrict__ ec, float* __restrict__ Tout,
    float coef, float beta)
{
  int g = blockIdx.x * 256 + threadIdx.x;   // b*N + n
  if (g >= BATCH * N) return;
  int b = g / N;
  int n = g % N;
  const int* e = ec + n * 6;
  const float* Tb = Tin + (size_t)b * N * 3;
  float s0 = 0.f, s1 = 0.f, s2 = 0.f;
#pragma unroll
  for (int d = 0; d < 6; ++d) {
    int c = e[d];
    const float* p = Tb + (size_t)c * 3;
    s0 += p[0]; s1 += p[1]; s2 += p[2];
  }
  size_t o = (size_t)g * 3;
  Tout[o + 0] = coef * s0 + beta * Tpp[o + 0];
  Tout[o + 1] = coef * s1 + beta * Tpp[o + 1];
  Tout[o + 2] = coef * s2 + beta * Tpp[o + 2];
}

// ---------------- Chebyshev recurrence step, FIN divisible by 4 ----------------
template<int N, int FIN>
__global__ void __launch_bounds__(256) cheb_step_v(
    const float* __restrict__ Tin, const float* __restrict__ Tpp,
    const int* __restrict__ ec, float* __restrict__ Tout,
    float coef, float beta)
{
  constexpr int F4 = FIN / 4;
  int idx = blockIdx.x * 256 + threadIdx.x;      // float4 index into [B][N][FIN]
  if (idx >= BATCH * N * F4) return;
  int g  = idx / F4;     // b*N + n
  int f4 = idx % F4;
  int n = g % N;
  int b = g / N;
  const int* e = ec + n * 6;
  const float4* Tin4 = (const float4*)Tin;
  float4 s = make_float4(0.f, 0.f, 0.f, 0.f);
#pragma unroll
  for (int d = 0; d < 6; ++d) {
    int c = e[d];
    float4 v = Tin4[(size_t)(b * N + c) * F4 + f4];
    s.x += v.x; s.y += v.y; s.z += v.z; s.w += v.w;
  }
  float4 p = ((const float4*)Tpp)[idx];
  float4 r;
  r.x = coef * s.x + beta * p.x;
  r.y = coef * s.y + beta * p.y;
  r.z = coef * s.z + beta * p.z;
  r.w = coef * s.w + beta * p.w;
  ((float4*)Tout)[idx] = r;
}

// ---------------- fused pool(conv+relu), FIN=3 (layer 0) ----------------
// out[b,m,fo] = sum_{j<3} pv[3m+j] * relu( bias[fo] + sum_k sum_f T_k[b,pc[3m+j],f] W[k,f,fo] )
template<int N, int M, int FOUT>
__global__ void __launch_bounds__(256) pool_conv_relu_f3(
    const float* __restrict__ X, const float* __restrict__ T,
    const float* __restrict__ W, const float* __restrict__ bias,
    const int* __restrict__ pc, const float* __restrict__ pv,
    float* __restrict__ out)
{
  constexpr int FIN = 3;
  constexpr int F4 = FOUT / 4;
  constexpr int BN = BATCH * N;
  __shared__ float Ws[6 * FIN * FOUT];
  for (int i = threadIdx.x; i < 6 * FIN * FOUT; i += 256) Ws[i] = W[i];
  __syncthreads();
  int t = blockIdx.x * 256 + threadIdx.x;       // (b*M + m)*F4 + f4
  if (t >= BATCH * M * F4) return;
  int f4 = t % F4;
  int gm = t / F4;
  int m = gm % M;
  int b = gm / M;
  const float4 b4 = ((const float4*)bias)[f4];
  int c0 = pc[m * 3 + 0], c1 = pc[m * 3 + 1], c2 = pc[m * 3 + 2];
  float v0 = pv[m * 3 + 0], v1 = pv[m * 3 + 1], v2 = pv[m * 3 + 2];
  float4 a0 = b4, a1 = b4, a2 = b4;
  const float4* Ws4 = (const float4*)Ws;
#pragma unroll
  for (int k = 0; k < 6; ++k) {
    const float* base = (k == 0) ? X : (T + (size_t)(k - 1) * BN * FIN);
    const float* r0 = base + ((size_t)b * N + c0) * FIN;
    const float* r1 = base + ((size_t)b * N + c1) * FIN;
    const float* r2 = base + ((size_t)b * N + c2) * FIN;
#pragma unroll
    for (int f = 0; f < FIN; ++f) {
      float4 w = Ws4[(k * FIN + f) * F4 + f4];
      fma4(a0, r0[f], w);
      fma4(a1, r1[f], w);
      fma4(a2, r2[f], w);
    }
  }
  a0 = relu4(a0); a1 = relu4(a1); a2 = relu4(a2);
  float4 acc;
  acc.x = v0 * a0.x + v1 * a1.x + v2 * a2.x;
  acc.y = v0 * a0.y + v1 * a1.y + v2 * a2.y;
  acc.z = v0 * a0.z + v1 * a1.z + v2 * a2.z;
  acc.w = v0 * a0.w + v1 * a1.w + v2 * a2.w;
  ((float4*)out)[t] = acc;
}

// ---------------- fused pool(conv+relu), FIN divisible by 4 ----------------
template<int N, int M, int FIN, int FOUT>
__global__ void __launch_bounds__(256) pool_conv_relu_v(
    const float* __restrict__ X, const float* __restrict__ T,
    const float* __restrict__ W, const float* __restrict__ bias,
    const int* __restrict__ pc, const float* __restrict__ pv,
    float* __restrict__ out)
{
  constexpr int F4 = FOUT / 4;
  constexpr int Fi4 = FIN / 4;
  constexpr int BN = BATCH * N;
  __shared__ float Ws[6 * FIN * FOUT];      // max 48 KB (layer 3)
  for (int i = threadIdx.x; i < 6 * FIN * FOUT; i += 256) Ws[i] = W[i];
  __syncthreads();
  int t = blockIdx.x * 256 + threadIdx.x;
  if (t >= BATCH * M * F4) return;
  int f4 = t % F4;
  int gm = t / F4;
  int m = gm % M;
  int b = gm / M;
  const float4 b4 = ((const float4*)bias)[f4];
  int c0 = pc[m * 3 + 0], c1 = pc[m * 3 + 1], c2 = pc[m * 3 + 2];
  float v0 = pv[m * 3 + 0], v1 = pv[m * 3 + 1], v2 = pv[m * 3 + 2];
  float4 a0 = b4, a1 = b4, a2 = b4;
  const float4* Ws4 = (const float4*)Ws;
  for (int k = 0; k < 6; ++k) {
    const float* base = (k == 0) ? X : (T + (size_t)(k - 1) * BN * FIN);
    const float4* r0 = (const float4*)(base + ((size_t)b * N + c0) * FIN);
    const float4* r1 = (const float4*)(base + ((size_t)b * N + c1) * FIN);
    const float4* r2 = (const float4*)(base + ((size_t)b * N + c2) * FIN);
#pragma unroll
    for (int fi = 0; fi < Fi4; ++fi) {
      float4 t0 = r0[fi], t1 = r1[fi], t2 = r2[fi];
#pragma unroll
      for (int ff = 0; ff < 4; ++ff) {
        float4 w = Ws4[(k * FIN + fi * 4 + ff) * F4 + f4];
        float e0 = ((const float*)&t0)[ff];
        float e1 = ((const float*)&t1)[ff];
        float e2 = ((const float*)&t2)[ff];
        fma4(a0, e0, w);
        fma4(a1, e1, w);
        fma4(a2, e2, w);
      }
    }
  }
  a0 = relu4(a0); a1 = relu4(a1); a2 = relu4(a2);
  float4 acc;
  acc.x = v0 * a0.x + v1 * a1.x + v2 * a2.x;
  acc.y = v0 * a0.y + v1 * a1.y + v2 * a2.y;
  acc.z = v0 * a0.z + v1 * a1.z + v2 * a2.z;
  acc.w = v0 * a0.w + v1 * a1.w + v2 * a2.w;
  ((float4*)out)[t] = acc;
}

// ---------------- encoder split-K partial ----------------
// partial[b][ks][fo] = sum_{i in rows(ks)} Xf[b,i] * encW[i,fo]
__global__ void __launch_bounds__(256) encoder_partial(
    const float* __restrict__ Xf, const float* __restrict__ encW,
    float* __restrict__ partial)
{
  int b  = blockIdx.x;        // 0..31
  int ks = blockIdx.y;        // 0..15
  int fo = threadIdx.x & 127;
  int half = threadIdx.x >> 7;
  const float* xr = Xf + b * 4096 + ks * 256 + half * 128;
  const float* w  = encW + (size_t)(ks * 256 + half * 128) * 128;
  float acc = 0.f;
#pragma unroll 8
  for (int i = 0; i < 128; ++i) acc += xr[i] * w[(size_t)i * 128 + fo];
  __shared__ float part[256];
  part[threadIdx.x] = acc;
  __syncthreads();
  if (half == 0) partial[(size_t)(b * 16 + ks) * 128 + fo] = part[fo] + part[128 + fo];
}

// ---------------- fused encoder-reduce + relu + classifier ----------------
__global__ void __launch_bounds__(128) encoder_reduce_cls(
    const float* __restrict__ partial, const float* __restrict__ encB,
    const float* __restrict__ clsW, const float* __restrict__ clsB,
    float* __restrict__ out)
{
  int b = blockIdx.x;           // 0..31
  int fo = threadIdx.x;         // 0..127
  float acc = encB[fo];
#pragma unroll
  for (int ks = 0; ks < 16; ++ks) acc += partial[(size_t)(b * 16 + ks) * 128 + fo];
  __shared__ float Hs[128];
  Hs[fo] = fmaxf(acc, 0.f);
  __syncthreads();
  if (fo < 10) {
    float s = clsB[fo];
#pragma unroll 4
    for (int f = 0; f < 128; ++f) s += Hs[f] * clsW[f * 10 + fo];
    out[b * 10 + fo] = s;
  }
}

extern "C" void kernel_launch(void* const* d_in, const int* in_sizes, int n_in,
                              void* d_out, int out_size, void* d_ws, size_t ws_size,
                              hipStream_t stream)
{
  const float* x   = (const float*)d_in[0];
  const int* ec0 = (const int*)d_in[2];
  const int* ec1 = (const int*)d_in[4];
  const int* ec2 = (const int*)d_in[6];
  const int* ec3 = (const int*)d_in[8];
  const int* pc0 = (const int*)d_in[10]; const float* pv0 = (const float*)d_in[11];
  const int* pc1 = (const int*)d_in[13]; const float* pv1 = (const float*)d_in[14];
  const int* pc2 = (const int*)d_in[16]; const float* pv2 = (const float*)d_in[17];
  const int* pc3 = (const int*)d_in[19]; const float* pv3 = (const float*)d_in[20];
  const float* W0 = (const float*)d_in[21]; const float* b0 = (const float*)d_in[22];
  const float* W1 = (const float*)d_in[23]; const float* b1 = (const float*)d_in[24];
  const float* W2 = (const float*)d_in[25]; const float* b2 = (const float*)d_in[26];
  const float* W3 = (const float*)d_in[27]; const float* b3 = (const float*)d_in[28];
  const float* encW = (const float*)d_in[29]; const float* encB = (const float*)d_in[30];
  const float* clsW = (const float*)d_in[31]; const float* clsB = (const float*)d_in[32];
  float* out = (float*)d_out;

  float* ws = (float*)d_ws;
  float* T  = ws;                    // 20,971,520 floats (max: layer 1)
  float* Xa = ws + 20971520;         // 4,194,304
  float* Xb = Xa + 4194304;          // 1,048,576
  float* P  = Xb + 1048576;          // 65,536

  const float cI = -1.0f / 6.0f;     // T1 = L x  = -1/6 * gather-sum
  const float cS = -1.0f / 3.0f;     // Tk = 2 L T(k-1) - T(k-2): 2*(-1/6) = -1/3

  // ================= layer 0: N=16384, FIN=3, FOUT=32, M=4096 =================
  {
    constexpr int N = 16384;
    constexpr int BN = BATCH * N;          // 524288
    const size_t S = (size_t)BN * 3;
    dim3 gs(BN / 256), blk(256);
    cheb_step_f3<N><<<gs, blk, 0, stream>>>(x,         x,         ec0, T,         cI,  0.f);
    cheb_step_f3<N><<<gs, blk, 0, stream>>>(T,         x,         ec0, T + S,     cS, -1.f);
    cheb_step_f3<N><<<gs, blk, 0, stream>>>(T + S,     T,         ec0, T + 2 * S, cS, -1.f);
    cheb_step_f3<N><<<gs, blk, 0, stream>>>(T + 2 * S, T + S,     ec0, T + 3 * S, cS, -1.f);
    cheb_step_f3<N><<<gs, blk, 0, stream>>>(T + 3 * S, T + 2 * S, ec0, T + 4 * S, cS, -1.f);
    // fused pool(relu(conv)): 32*4096*8 threads = 4096 blocks
    pool_conv_relu_f3<N, 4096, 32><<<dim3(BATCH * 4096 * 8 / 256), blk, 0, stream>>>(
        x, T, W0, b0, pc0, pv0, Xa);
  }
  // ================= layer 1: N=4096, FIN=32, FOUT=32, M=1024 =================
  {
    constexpr int N = 4096;
    constexpr int BN = BATCH * N;          // 131072
    const size_t S = (size_t)BN * 32;
    dim3 gs((BN * 8) / 256), blk(256);
    cheb_step_v<N, 32><<<gs, blk, 0, stream>>>(Xa,        Xa,        ec1, T,         cI,  0.f);
    cheb_step_v<N, 32><<<gs, blk, 0, stream>>>(T,         Xa,        ec1, T + S,     cS, -1.f);
    cheb_step_v<N, 32><<<gs, blk, 0, stream>>>(T + S,     T,         ec1, T + 2 * S, cS, -1.f);
    cheb_step_v<N, 32><<<gs, blk, 0, stream>>>(T + 2 * S, T + S,     ec1, T + 3 * S, cS, -1.f);
    cheb_step_v<N, 32><<<gs, blk, 0, stream>>>(T + 3 * S, T + 2 * S, ec1, T + 4 * S, cS, -1.f);
    pool_conv_relu_v<N, 1024, 32, 32><<<dim3(BATCH * 1024 * 8 / 256), blk, 0, stream>>>(
        Xa, T, W1, b1, pc1, pv1, Xb);
  }
  // ================= layer 2: N=1024, FIN=32, FOUT=32, M=256 =================
  {
    constexpr int N = 1024;
    constexpr int BN = BATCH * N;          // 32768
    const size_t S = (size_t)BN * 32;
    dim3 gs((BN * 8) / 256), blk(256);
    cheb_step_v<N, 32><<<gs, blk, 0, stream>>>(Xb,        Xb,        ec2, T,         cI,  0.f);
    cheb_step_v<N, 32><<<gs, blk, 0, stream>>>(T,         Xb,        ec2, T + S,     cS, -1.f);
    cheb_step_v<N, 32><<<gs, blk, 0, stream>>>(T + S,     T,         ec2, T + 2 * S, cS, -1.f);
    cheb_step_v<N, 32><<<gs, blk, 0, stream>>>(T + 2 * S, T + S,     ec2, T + 3 * S, cS, -1.f);
    cheb_step_v<N, 32><<<gs, blk, 0, stream>>>(T + 3 * S, T + 2 * S, ec2, T + 4 * S, cS, -1.f);
    pool_conv_relu_v<N, 256, 32, 32><<<dim3(BATCH * 256 * 8 / 256), blk, 0, stream>>>(
        Xb, T, W2, b2, pc2, pv2, Xa);
  }
  // ================= layer 3: N=256, FIN=32, FOUT=64, M=64 =================
  {
    constexpr int N = 256;
    constexpr int BN = BATCH * N;          // 8192
    const size_t S = (size_t)BN * 32;
    dim3 gs((BN * 8) / 256), blk(256);
    cheb_step_v<N, 32><<<gs, blk, 0, stream>>>(Xa,        Xa,        ec3, T,         cI,  0.f);
    cheb_step_v<N, 32><<<gs, blk, 0, stream>>>(T,         Xa,        ec3, T + S,     cS, -1.f);
    cheb_step_v<N, 32><<<gs, blk, 0, stream>>>(T + S,     T,         ec3, T + 2 * S, cS, -1.f);
    cheb_step_v<N, 32><<<gs, blk, 0, stream>>>(T + 2 * S, T + S,     ec3, T + 3 * S, cS, -1.f);
    cheb_step_v<N, 32><<<gs, blk, 0, stream>>>(T + 3 * S, T + 2 * S, ec3, T + 4 * S, cS, -1.f);
    pool_conv_relu_v<N, 64, 32, 64><<<dim3(BATCH * 64 * 16 / 256), blk, 0, stream>>>(
        Xa, T, W3, b3, pc3, pv3, Xb);
  }
  // ================= head =================
  encoder_partial<<<dim3(32, 16), dim3(256), 0, stream>>>(Xb, encW, P);
  encoder_reduce_cls<<<dim3(32), dim3(128), 0, stream>>>(P, encB, clsW, clsB, out);
}